// Round 1
// baseline (448.661 us; speedup 1.0000x reference)
//
#include <hip/hip_runtime.h>
#include <hip/hip_bf16.h>

#define HID 128

// ---------------- CSR build ----------------

__global__ void deg_init_kernel(int* deg, int N) {
    int i = blockIdx.x * blockDim.x + threadIdx.x;
    if (i < N) deg[i] = 1;  // self loop
}

__global__ void deg_count_kernel(const int* __restrict__ dst, int E, int* deg) {
    int i = blockIdx.x * blockDim.x + threadIdx.x;
    if (i < E) atomicAdd(&deg[dst[i]], 1);
}

// single-block exclusive scan over N degrees -> row_ptr, cursor, writes self-loop col
__global__ __launch_bounds__(1024) void scan_kernel(const int* __restrict__ deg,
                                                    int* row_ptr, int* cursor, int* col, int N) {
    __shared__ int sums[1024];
    int tid = threadIdx.x;
    int chunk = (N + 1023) >> 10;
    int lo = tid * chunk;
    int hi = min(lo + chunk, N);
    int s = 0;
    for (int i = lo; i < hi; ++i) s += deg[i];
    sums[tid] = s;
    __syncthreads();
    for (int off = 1; off < 1024; off <<= 1) {
        int v = (tid >= off) ? sums[tid - off] : 0;
        __syncthreads();
        sums[tid] += v;
        __syncthreads();
    }
    int run = (tid == 0) ? 0 : sums[tid - 1];
    for (int i = lo; i < hi; ++i) {
        int d = deg[i];
        row_ptr[i] = run;
        cursor[i] = run + 1;   // slot 0 taken by self loop
        col[run] = i;          // self loop
        run += d;
    }
    if (tid == 1023) row_ptr[N] = sums[1023];
}

__global__ void scatter_kernel(const int* __restrict__ src, const int* __restrict__ dst,
                               int E, int* cursor, int* col) {
    int i = blockIdx.x * blockDim.x + threadIdx.x;
    if (i < E) {
        int pos = atomicAdd(&cursor[dst[i]], 1);
        col[pos] = src[i];
    }
}

// ---------------- GEMM: h = x @ W  (N x 128 @ 128 x 128) ----------------
// block = 256 threads, 32 rows/block. x tile in LDS; W streamed via L1/L2.
__global__ __launch_bounds__(256) void gemm_kernel(const float* __restrict__ x,
                                                   const float* __restrict__ W,
                                                   float* __restrict__ h, int N) {
    __shared__ __align__(16) float xs[32][HID];
    int tid = threadIdx.x;
    int row0 = blockIdx.x * 32;
    // stage x tile (32x128 f32 = 16 KiB), 4 float4 per thread
    #pragma unroll
    for (int t = 0; t < 4; ++t) {
        int f = tid + t * 256;         // float4 index 0..1023
        int r = f >> 5;
        int c4 = (f & 31) << 2;
        float4 v = make_float4(0.f, 0.f, 0.f, 0.f);
        int row = row0 + r;
        if (row < N) v = *(const float4*)&x[(size_t)row * HID + c4];
        *(float4*)&xs[r][c4] = v;
    }
    __syncthreads();

    int tx = tid & 31;   // output col group: cols tx*4..tx*4+3
    int ty = tid >> 5;   // row group: rows ty*4..ty*4+3
    float acc[4][4] = {};

    for (int k4 = 0; k4 < HID; k4 += 4) {
        float xv[4][4];
        #pragma unroll
        for (int r = 0; r < 4; ++r) {
            float4 v = *(const float4*)&xs[ty * 4 + r][k4];
            xv[r][0] = v.x; xv[r][1] = v.y; xv[r][2] = v.z; xv[r][3] = v.w;
        }
        #pragma unroll
        for (int kk = 0; kk < 4; ++kk) {
            float4 w = *(const float4*)&W[(size_t)(k4 + kk) * HID + (tx << 2)];
            #pragma unroll
            for (int r = 0; r < 4; ++r) {
                acc[r][0] += xv[r][kk] * w.x;
                acc[r][1] += xv[r][kk] * w.y;
                acc[r][2] += xv[r][kk] * w.z;
                acc[r][3] += xv[r][kk] * w.w;
            }
        }
    }
    #pragma unroll
    for (int r = 0; r < 4; ++r) {
        int row = row0 + ty * 4 + r;
        if (row < N) {
            *(float4*)&h[(size_t)row * HID + (tx << 2)] =
                make_float4(acc[r][0], acc[r][1], acc[r][2], acc[r][3]);
        }
    }
}

// ---------------- per-node attention coefficients ----------------
// alpha_src[n][hd] = sum_c h[n,hd,c]*a_src[hd,c]; a_* flat-indexed by global channel.
template <int H>
__global__ __launch_bounds__(256) void alphas_kernel(const float* __restrict__ h,
                                                     const float* __restrict__ a_src,
                                                     const float* __restrict__ a_dst,
                                                     float* __restrict__ asrc,
                                                     float* __restrict__ adst, int N) {
    int lane = threadIdx.x & 63;
    int node = blockIdx.x * (blockDim.x >> 6) + (threadIdx.x >> 6);
    if (node >= N) return;
    float2 hv = *(const float2*)&h[(size_t)node * HID + 2 * lane];
    float pa = hv.x * a_src[2 * lane] + hv.y * a_src[2 * lane + 1];
    float pd = hv.x * a_dst[2 * lane] + hv.y * a_dst[2 * lane + 1];
    constexpr int GROUP = 64 / H;   // lanes per head
    #pragma unroll
    for (int off = 1; off < GROUP; off <<= 1) {
        pa += __shfl_xor(pa, off);
        pd += __shfl_xor(pd, off);
    }
    if ((lane & (GROUP - 1)) == 0) {
        int hd = lane / GROUP;
        asrc[(size_t)node * H + hd] = pa;
        adst[(size_t)node * H + hd] = pd;
    }
}

// ---------------- aggregation: one wave per dst node, online softmax ----------------
template <int H, bool RELU>
__global__ __launch_bounds__(256) void aggregate_kernel(const float* __restrict__ h,
                                                        const float* __restrict__ asrc,
                                                        const float* __restrict__ adst,
                                                        const int* __restrict__ row_ptr,
                                                        const int* __restrict__ col,
                                                        const float* __restrict__ bias,
                                                        float* __restrict__ out, int N) {
    int lane = threadIdx.x & 63;
    int node = blockIdx.x * (blockDim.x >> 6) + (threadIdx.x >> 6);
    if (node >= N) return;

    int start = row_ptr[node];
    int end   = row_ptr[node + 1];

    constexpr int EPC = 64 / H;        // edges per chunk
    int ehd  = lane % H;               // e-phase: head handled by this lane
    int eidx = lane / H;               // e-phase: edge slot
    int ahd  = (lane * H) >> 6;        // accumulate-phase head (lane covers ch 2l,2l+1)

    float adst_n = adst[(size_t)node * H + ehd];

    float m = -INFINITY, denom = 0.f;
    float2 acc = make_float2(0.f, 0.f);

    for (int base = start; base < end; base += EPC) {
        int idx = base + eidx;
        bool valid = idx < end;
        int s = valid ? col[idx] : 0;
        float e = -INFINITY;
        if (valid) {
            float t = asrc[(size_t)s * H + ehd] + adst_n;
            e = (t >= 0.f) ? t : 0.2f * t;
        }
        // chunk max per head (lanes with same ehd form xor-coset with strides H..32)
        float cmax = e;
        #pragma unroll
        for (int off = H; off < 64; off <<= 1) cmax = fmaxf(cmax, __shfl_xor(cmax, off));
        float nm = fmaxf(m, cmax);
        float p = valid ? __expf(e - nm) : 0.f;
        float csum = p;
        #pragma unroll
        for (int off = H; off < 64; off <<= 1) csum += __shfl_xor(csum, off);
        float scale_e = __expf(m - nm);     // first chunk: exp(-inf)=0
        denom = denom * scale_e + csum;
        m = nm;
        // rescale accumulator (scale for head ahd lives at lane ahd)
        float scale_a = __shfl(scale_e, ahd);
        acc.x *= scale_a;
        acc.y *= scale_a;
        int cnt = min(end - base, EPC);
        for (int i = 0; i < cnt; ++i) {
            int   si = __shfl(s, i * H);
            float pi = __shfl(p, i * H + ahd);
            float2 hv = *(const float2*)&h[(size_t)si * HID + 2 * lane];
            acc.x += pi * hv.x;
            acc.y += pi * hv.y;
        }
    }
    float den = __shfl(denom, ahd);
    float inv = 1.f / den;
    float2 bv = *(const float2*)&bias[2 * lane];
    float o0 = acc.x * inv + bv.x;
    float o1 = acc.y * inv + bv.y;
    if (RELU) { o0 = fmaxf(o0, 0.f); o1 = fmaxf(o1, 0.f); }
    *(float2*)&out[(size_t)node * HID + 2 * lane] = make_float2(o0, o1);
}

// ---------------- launch ----------------

extern "C" void kernel_launch(void* const* d_in, const int* in_sizes, int n_in,
                              void* d_out, int out_size, void* d_ws, size_t ws_size,
                              hipStream_t stream) {
    const float* x   = (const float*)d_in[0];
    const int*   ei  = (const int*)d_in[1];
    const float* W1  = (const float*)d_in[2];
    const float* as1 = (const float*)d_in[3];
    const float* ad1 = (const float*)d_in[4];
    const float* b1  = (const float*)d_in[5];
    const float* W2  = (const float*)d_in[6];
    const float* as2 = (const float*)d_in[7];
    const float* ad2 = (const float*)d_in[8];
    const float* b2  = (const float*)d_in[9];
    const float* W3  = (const float*)d_in[10];
    const float* as3 = (const float*)d_in[11];
    const float* ad3 = (const float*)d_in[12];
    const float* b3  = (const float*)d_in[13];

    int N = in_sizes[0] / HID;
    int E = in_sizes[1] / 2;
    const int* srcv = ei;
    const int* dstv = ei + E;

    char* ws = (char*)d_ws;
    size_t ofs = 0;
    auto alloc = [&](size_t bytes) -> void* {
        void* p = ws + ofs;
        ofs = (ofs + bytes + 255) & ~(size_t)255;
        return p;
    };
    int*   rp  = (int*)alloc((size_t)(N + 1) * 4);
    int*   cur = (int*)alloc((size_t)N * 4);
    int*   deg = (int*)alloc((size_t)N * 4);
    int*   col = (int*)alloc((size_t)(E + N) * 4);
    float* h   = (float*)alloc((size_t)N * HID * 4);
    float* pa  = (float*)alloc((size_t)N * 4 * 4);
    float* pd  = (float*)alloc((size_t)N * 4 * 4);
    float* y   = (float*)d_out;   // layers 1-2 output aliases d_out (overwritten by layer 3)

    // CSR build
    deg_init_kernel<<<(N + 255) / 256, 256, 0, stream>>>(deg, N);
    deg_count_kernel<<<(E + 255) / 256, 256, 0, stream>>>(dstv, E, deg);
    scan_kernel<<<1, 1024, 0, stream>>>(deg, rp, cur, col, N);
    scatter_kernel<<<(E + 255) / 256, 256, 0, stream>>>(srcv, dstv, E, cur, col);

    int gGemm = (N + 31) / 32;
    int gWave = (N + 3) / 4;

    // layer 1 (4 heads, relu)
    gemm_kernel<<<gGemm, 256, 0, stream>>>(x, W1, h, N);
    alphas_kernel<4><<<gWave, 256, 0, stream>>>(h, as1, ad1, pa, pd, N);
    aggregate_kernel<4, true><<<gWave, 256, 0, stream>>>(h, pa, pd, rp, col, b1, y, N);
    // layer 2 (4 heads, relu)
    gemm_kernel<<<gGemm, 256, 0, stream>>>(y, W2, h, N);
    alphas_kernel<4><<<gWave, 256, 0, stream>>>(h, as2, ad2, pa, pd, N);
    aggregate_kernel<4, true><<<gWave, 256, 0, stream>>>(h, pa, pd, rp, col, b2, y, N);
    // layer 3 (1 head, no relu)
    gemm_kernel<<<gGemm, 256, 0, stream>>>(y, W3, h, N);
    alphas_kernel<1><<<gWave, 256, 0, stream>>>(h, as3, ad3, pa, pd, N);
    aggregate_kernel<1, false><<<gWave, 256, 0, stream>>>(h, pa, pd, rp, col, b3,
                                                          (float*)d_out, N);
}

// Round 2
// 325.300 us; speedup vs baseline: 1.3792x; 1.3792x over previous
//
#include <hip/hip_runtime.h>
#include <hip/hip_bf16.h>

#define HID 128

// ---------------- CSR build ----------------

__global__ void deg_init_kernel(int* deg, int N) {
    int i = blockIdx.x * blockDim.x + threadIdx.x;
    if (i < N) deg[i] = 1;  // self loop
}

__global__ void deg_count_kernel(const int* __restrict__ dst, int E, int* deg) {
    int i = blockIdx.x * blockDim.x + threadIdx.x;
    if (i < E) atomicAdd(&deg[dst[i]], 1);
}

// --- two-level exclusive scan over N degrees -> row_ptr, cursor, self-loop col ---
// scan1: per-block (256 elems) total
__global__ __launch_bounds__(256) void scan1_kernel(const int* __restrict__ deg,
                                                    int* __restrict__ bsum, int N) {
    int tid = threadIdx.x;
    int i = blockIdx.x * 256 + tid;
    int v = (i < N) ? deg[i] : 0;
    #pragma unroll
    for (int off = 1; off < 64; off <<= 1) v += __shfl_xor(v, off);
    __shared__ int ws[4];
    if ((tid & 63) == 0) ws[tid >> 6] = v;
    __syncthreads();
    if (tid == 0) bsum[blockIdx.x] = ws[0] + ws[1] + ws[2] + ws[3];
}

// scan2: single-block exclusive scan of NB (<=256) block sums
__global__ __launch_bounds__(256) void scan2_kernel(const int* __restrict__ bsum,
                                                    int* __restrict__ boff,
                                                    int* __restrict__ row_ptr, int NB, int N) {
    __shared__ int s[256];
    int tid = threadIdx.x;
    int v = (tid < NB) ? bsum[tid] : 0;
    s[tid] = v;
    __syncthreads();
    for (int off = 1; off < 256; off <<= 1) {
        int t = (tid >= off) ? s[tid - off] : 0;
        __syncthreads();
        s[tid] += t;
        __syncthreads();
    }
    if (tid < NB) boff[tid] = s[tid] - v;  // exclusive
    if (tid == NB - 1) row_ptr[N] = s[tid];
}

// scan3: per-block rescan + write row_ptr/cursor/self-loop
__global__ __launch_bounds__(256) void scan3_kernel(const int* __restrict__ deg,
                                                    const int* __restrict__ boff,
                                                    int* __restrict__ row_ptr,
                                                    int* __restrict__ cursor,
                                                    int* __restrict__ col, int N) {
    __shared__ int s[256];
    int tid = threadIdx.x;
    int i = blockIdx.x * 256 + tid;
    int d = (i < N) ? deg[i] : 0;
    s[tid] = d;
    __syncthreads();
    for (int off = 1; off < 256; off <<= 1) {
        int t = (tid >= off) ? s[tid - off] : 0;
        __syncthreads();
        s[tid] += t;
        __syncthreads();
    }
    if (i < N) {
        int run = boff[blockIdx.x] + s[tid] - d;  // exclusive prefix
        row_ptr[i] = run;
        cursor[i] = run + 1;  // slot 0 taken by self loop
        col[run] = i;         // self loop
    }
}

__global__ void scatter_kernel(const int* __restrict__ src, const int* __restrict__ dst,
                               int E, int* cursor, int* col) {
    int i = blockIdx.x * blockDim.x + threadIdx.x;
    if (i < E) {
        int pos = atomicAdd(&cursor[dst[i]], 1);
        col[pos] = src[i];
    }
}

// ---------------- GEMM: h = x @ W  (N x 128 @ 128 x 128) ----------------
// block = 256 threads, 32 rows/block. x tile in LDS; W streamed via L1/L2.
__global__ __launch_bounds__(256) void gemm_kernel(const float* __restrict__ x,
                                                   const float* __restrict__ W,
                                                   float* __restrict__ h, int N) {
    __shared__ __align__(16) float xs[32][HID];
    int tid = threadIdx.x;
    int row0 = blockIdx.x * 32;
    // stage x tile (32x128 f32 = 16 KiB), 4 float4 per thread
    #pragma unroll
    for (int t = 0; t < 4; ++t) {
        int f = tid + t * 256;         // float4 index 0..1023
        int r = f >> 5;
        int c4 = (f & 31) << 2;
        float4 v = make_float4(0.f, 0.f, 0.f, 0.f);
        int row = row0 + r;
        if (row < N) v = *(const float4*)&x[(size_t)row * HID + c4];
        *(float4*)&xs[r][c4] = v;
    }
    __syncthreads();

    int tx = tid & 31;   // output col group: cols tx*4..tx*4+3
    int ty = tid >> 5;   // row group: rows ty*4..ty*4+3
    float acc[4][4] = {};

    for (int k4 = 0; k4 < HID; k4 += 4) {
        float xv[4][4];
        #pragma unroll
        for (int r = 0; r < 4; ++r) {
            float4 v = *(const float4*)&xs[ty * 4 + r][k4];
            xv[r][0] = v.x; xv[r][1] = v.y; xv[r][2] = v.z; xv[r][3] = v.w;
        }
        #pragma unroll
        for (int kk = 0; kk < 4; ++kk) {
            float4 w = *(const float4*)&W[(size_t)(k4 + kk) * HID + (tx << 2)];
            #pragma unroll
            for (int r = 0; r < 4; ++r) {
                acc[r][0] += xv[r][kk] * w.x;
                acc[r][1] += xv[r][kk] * w.y;
                acc[r][2] += xv[r][kk] * w.z;
                acc[r][3] += xv[r][kk] * w.w;
            }
        }
    }
    #pragma unroll
    for (int r = 0; r < 4; ++r) {
        int row = row0 + ty * 4 + r;
        if (row < N) {
            *(float4*)&h[(size_t)row * HID + (tx << 2)] =
                make_float4(acc[r][0], acc[r][1], acc[r][2], acc[r][3]);
        }
    }
}

// ---------------- per-node attention coefficients ----------------
template <int H>
__global__ __launch_bounds__(256) void alphas_kernel(const float* __restrict__ h,
                                                     const float* __restrict__ a_src,
                                                     const float* __restrict__ a_dst,
                                                     float* __restrict__ asrc,
                                                     float* __restrict__ adst, int N) {
    int lane = threadIdx.x & 63;
    int node = blockIdx.x * (blockDim.x >> 6) + (threadIdx.x >> 6);
    if (node >= N) return;
    float2 hv = *(const float2*)&h[(size_t)node * HID + 2 * lane];
    float pa = hv.x * a_src[2 * lane] + hv.y * a_src[2 * lane + 1];
    float pd = hv.x * a_dst[2 * lane] + hv.y * a_dst[2 * lane + 1];
    constexpr int GROUP = 64 / H;   // lanes per head
    #pragma unroll
    for (int off = 1; off < GROUP; off <<= 1) {
        pa += __shfl_xor(pa, off);
        pd += __shfl_xor(pd, off);
    }
    if ((lane & (GROUP - 1)) == 0) {
        int hd = lane / GROUP;
        asrc[(size_t)node * H + hd] = pa;
        adst[(size_t)node * H + hd] = pd;
    }
}

// ---------------- aggregation: one wave per dst node, online softmax ----------------
template <int H, bool RELU>
__global__ __launch_bounds__(256) void aggregate_kernel(const float* __restrict__ h,
                                                        const float* __restrict__ asrc,
                                                        const float* __restrict__ adst,
                                                        const int* __restrict__ row_ptr,
                                                        const int* __restrict__ col,
                                                        const float* __restrict__ bias,
                                                        float* __restrict__ out, int N) {
    int lane = threadIdx.x & 63;
    int node = blockIdx.x * (blockDim.x >> 6) + (threadIdx.x >> 6);
    if (node >= N) return;

    int start = row_ptr[node];
    int end   = row_ptr[node + 1];

    constexpr int EPC = 64 / H;        // edges per chunk
    int ehd  = lane % H;               // e-phase: head handled by this lane
    int eidx = lane / H;               // e-phase: edge slot
    int ahd  = (lane * H) >> 6;        // accumulate-phase head (lane covers ch 2l,2l+1)

    float adst_n = adst[(size_t)node * H + ehd];

    float m = -INFINITY, denom = 0.f;
    float2 acc = make_float2(0.f, 0.f);

    for (int base = start; base < end; base += EPC) {
        int idx = base + eidx;
        bool valid = idx < end;
        int s = valid ? col[idx] : 0;
        float e = -INFINITY;
        if (valid) {
            float t = asrc[(size_t)s * H + ehd] + adst_n;
            e = (t >= 0.f) ? t : 0.2f * t;
        }
        float cmax = e;
        #pragma unroll
        for (int off = H; off < 64; off <<= 1) cmax = fmaxf(cmax, __shfl_xor(cmax, off));
        float nm = fmaxf(m, cmax);
        float p = valid ? __expf(e - nm) : 0.f;
        float csum = p;
        #pragma unroll
        for (int off = H; off < 64; off <<= 1) csum += __shfl_xor(csum, off);
        float scale_e = __expf(m - nm);     // first chunk: exp(-inf)=0
        denom = denom * scale_e + csum;
        m = nm;
        float scale_a = __shfl(scale_e, ahd);
        acc.x *= scale_a;
        acc.y *= scale_a;
        int cnt = min(end - base, EPC);
        for (int i = 0; i < cnt; ++i) {
            int   si = __shfl(s, i * H);
            float pi = __shfl(p, i * H + ahd);
            float2 hv = *(const float2*)&h[(size_t)si * HID + 2 * lane];
            acc.x += pi * hv.x;
            acc.y += pi * hv.y;
        }
    }
    float den = __shfl(denom, ahd);
    float inv = 1.f / den;
    float2 bv = *(const float2*)&bias[2 * lane];
    float o0 = acc.x * inv + bv.x;
    float o1 = acc.y * inv + bv.y;
    if (RELU) { o0 = fmaxf(o0, 0.f); o1 = fmaxf(o1, 0.f); }
    *(float2*)&out[(size_t)node * HID + 2 * lane] = make_float2(o0, o1);
}

// ---------------- launch ----------------

extern "C" void kernel_launch(void* const* d_in, const int* in_sizes, int n_in,
                              void* d_out, int out_size, void* d_ws, size_t ws_size,
                              hipStream_t stream) {
    const float* x   = (const float*)d_in[0];
    const int*   ei  = (const int*)d_in[1];
    const float* W1  = (const float*)d_in[2];
    const float* as1 = (const float*)d_in[3];
    const float* ad1 = (const float*)d_in[4];
    const float* b1  = (const float*)d_in[5];
    const float* W2  = (const float*)d_in[6];
    const float* as2 = (const float*)d_in[7];
    const float* ad2 = (const float*)d_in[8];
    const float* b2  = (const float*)d_in[9];
    const float* W3  = (const float*)d_in[10];
    const float* as3 = (const float*)d_in[11];
    const float* ad3 = (const float*)d_in[12];
    const float* b3  = (const float*)d_in[13];

    int N = in_sizes[0] / HID;
    int E = in_sizes[1] / 2;
    const int* srcv = ei;
    const int* dstv = ei + E;

    char* ws = (char*)d_ws;
    size_t ofs = 0;
    auto alloc = [&](size_t bytes) -> void* {
        void* p = ws + ofs;
        ofs = (ofs + bytes + 255) & ~(size_t)255;
        return p;
    };
    int NB = (N + 255) / 256;
    int*   rp   = (int*)alloc((size_t)(N + 1) * 4);
    int*   cur  = (int*)alloc((size_t)N * 4);
    int*   deg  = (int*)alloc((size_t)N * 4);
    int*   bsum = (int*)alloc((size_t)NB * 4);
    int*   boff = (int*)alloc((size_t)NB * 4);
    int*   col  = (int*)alloc((size_t)(E + N) * 4);
    float* h    = (float*)alloc((size_t)N * HID * 4);
    float* pa   = (float*)alloc((size_t)N * 4 * 4);
    float* pd   = (float*)alloc((size_t)N * 4 * 4);
    float* y    = (float*)d_out;   // layers 1-2 output aliases d_out (overwritten by layer 3)

    // CSR build
    deg_init_kernel<<<(N + 255) / 256, 256, 0, stream>>>(deg, N);
    deg_count_kernel<<<(E + 255) / 256, 256, 0, stream>>>(dstv, E, deg);
    scan1_kernel<<<NB, 256, 0, stream>>>(deg, bsum, N);
    scan2_kernel<<<1, 256, 0, stream>>>(bsum, boff, rp, NB, N);
    scan3_kernel<<<NB, 256, 0, stream>>>(deg, boff, rp, cur, col, N);
    scatter_kernel<<<(E + 255) / 256, 256, 0, stream>>>(srcv, dstv, E, cur, col);

    int gGemm = (N + 31) / 32;
    int gWave = (N + 3) / 4;

    // layer 1 (4 heads, relu)
    gemm_kernel<<<gGemm, 256, 0, stream>>>(x, W1, h, N);
    alphas_kernel<4><<<gWave, 256, 0, stream>>>(h, as1, ad1, pa, pd, N);
    aggregate_kernel<4, true><<<gWave, 256, 0, stream>>>(h, pa, pd, rp, col, b1, y, N);
    // layer 2 (4 heads, relu)
    gemm_kernel<<<gGemm, 256, 0, stream>>>(y, W2, h, N);
    alphas_kernel<4><<<gWave, 256, 0, stream>>>(h, as2, ad2, pa, pd, N);
    aggregate_kernel<4, true><<<gWave, 256, 0, stream>>>(h, pa, pd, rp, col, b2, y, N);
    // layer 3 (1 head, no relu)
    gemm_kernel<<<gGemm, 256, 0, stream>>>(y, W3, h, N);
    alphas_kernel<1><<<gWave, 256, 0, stream>>>(h, as3, ad3, pa, pd, N);
    aggregate_kernel<1, false><<<gWave, 256, 0, stream>>>(h, pa, pd, rp, col, b3,
                                                          (float*)d_out, N);
}

// Round 3
// 288.968 us; speedup vs baseline: 1.5526x; 1.1257x over previous
//
#include <hip/hip_runtime.h>
#include <hip/hip_bf16.h>

#define HID 128

// ---------------- CSR build ----------------

__global__ void deg_init_kernel(int* deg, int N) {
    int i = blockIdx.x * blockDim.x + threadIdx.x;
    if (i < N) deg[i] = 1;  // self loop
}

__global__ void deg_count_kernel(const int* __restrict__ dst, int E, int* deg) {
    int i = blockIdx.x * blockDim.x + threadIdx.x;
    if (i < E) atomicAdd(&deg[dst[i]], 1);
}

// --- two-level exclusive scan over N degrees -> row_ptr, cursor, self-loop col ---
__global__ __launch_bounds__(256) void scan1_kernel(const int* __restrict__ deg,
                                                    int* __restrict__ bsum, int N) {
    int tid = threadIdx.x;
    int i = blockIdx.x * 256 + tid;
    int v = (i < N) ? deg[i] : 0;
    #pragma unroll
    for (int off = 1; off < 64; off <<= 1) v += __shfl_xor(v, off);
    __shared__ int ws[4];
    if ((tid & 63) == 0) ws[tid >> 6] = v;
    __syncthreads();
    if (tid == 0) bsum[blockIdx.x] = ws[0] + ws[1] + ws[2] + ws[3];
}

__global__ __launch_bounds__(256) void scan2_kernel(const int* __restrict__ bsum,
                                                    int* __restrict__ boff,
                                                    int* __restrict__ row_ptr, int NB, int N) {
    __shared__ int s[256];
    int tid = threadIdx.x;
    int v = (tid < NB) ? bsum[tid] : 0;
    s[tid] = v;
    __syncthreads();
    for (int off = 1; off < 256; off <<= 1) {
        int t = (tid >= off) ? s[tid - off] : 0;
        __syncthreads();
        s[tid] += t;
        __syncthreads();
    }
    if (tid < NB) boff[tid] = s[tid] - v;  // exclusive
    if (tid == NB - 1) row_ptr[N] = s[tid];
}

__global__ __launch_bounds__(256) void scan3_kernel(const int* __restrict__ deg,
                                                    const int* __restrict__ boff,
                                                    int* __restrict__ row_ptr,
                                                    int* __restrict__ cursor,
                                                    int* __restrict__ col, int N) {
    __shared__ int s[256];
    int tid = threadIdx.x;
    int i = blockIdx.x * 256 + tid;
    int d = (i < N) ? deg[i] : 0;
    s[tid] = d;
    __syncthreads();
    for (int off = 1; off < 256; off <<= 1) {
        int t = (tid >= off) ? s[tid - off] : 0;
        __syncthreads();
        s[tid] += t;
        __syncthreads();
    }
    if (i < N) {
        int run = boff[blockIdx.x] + s[tid] - d;  // exclusive prefix
        row_ptr[i] = run;
        cursor[i] = run + 1;  // slot 0 taken by self loop
        col[run] = i;         // self loop
    }
}

__global__ void scatter_kernel(const int* __restrict__ src, const int* __restrict__ dst,
                               int E, int* cursor, int* col) {
    int i = blockIdx.x * blockDim.x + threadIdx.x;
    if (i < E) {
        int pos = atomicAdd(&cursor[dst[i]], 1);
        col[pos] = src[i];
    }
}

// ---------------- GEMM + fused alpha: h = x @ W, alpha = <h, a> ----------------
// block = 256 threads, 32 rows/block. x tile in LDS; W streamed via L1/L2.
// Epilogue: each row is held by a contiguous 32-lane half-wave (ty) across tx;
// per-head shfl_xor reduce produces alpha_src/alpha_dst without re-reading h.
template <int H>
__global__ __launch_bounds__(256) void gemm_alphas_kernel(const float* __restrict__ x,
                                                          const float* __restrict__ W,
                                                          const float* __restrict__ a_src,
                                                          const float* __restrict__ a_dst,
                                                          float* __restrict__ h,
                                                          float* __restrict__ pa_out,
                                                          float* __restrict__ pd_out, int N) {
    __shared__ __align__(16) float xs[32][HID];
    int tid = threadIdx.x;
    int row0 = blockIdx.x * 32;
    #pragma unroll
    for (int t = 0; t < 4; ++t) {
        int f = tid + t * 256;
        int r = f >> 5;
        int c4 = (f & 31) << 2;
        float4 v = make_float4(0.f, 0.f, 0.f, 0.f);
        int row = row0 + r;
        if (row < N) v = *(const float4*)&x[(size_t)row * HID + c4];
        *(float4*)&xs[r][c4] = v;
    }
    __syncthreads();

    int tx = tid & 31;
    int ty = tid >> 5;
    float acc[4][4] = {};

    for (int k4 = 0; k4 < HID; k4 += 4) {
        float xv[4][4];
        #pragma unroll
        for (int r = 0; r < 4; ++r) {
            float4 v = *(const float4*)&xs[ty * 4 + r][k4];
            xv[r][0] = v.x; xv[r][1] = v.y; xv[r][2] = v.z; xv[r][3] = v.w;
        }
        #pragma unroll
        for (int kk = 0; kk < 4; ++kk) {
            float4 w = *(const float4*)&W[(size_t)(k4 + kk) * HID + (tx << 2)];
            #pragma unroll
            for (int r = 0; r < 4; ++r) {
                acc[r][0] += xv[r][kk] * w.x;
                acc[r][1] += xv[r][kk] * w.y;
                acc[r][2] += xv[r][kk] * w.z;
                acc[r][3] += xv[r][kk] * w.w;
            }
        }
    }

    float4 av = *(const float4*)&a_src[tx << 2];
    float4 dv = *(const float4*)&a_dst[tx << 2];
    constexpr int G = 32 / H;            // lanes per head (within the 32-lane row group)
    #pragma unroll
    for (int r = 0; r < 4; ++r) {
        int row = row0 + ty * 4 + r;
        // per-head partial dots
        float pa = acc[r][0] * av.x + acc[r][1] * av.y + acc[r][2] * av.z + acc[r][3] * av.w;
        float pd = acc[r][0] * dv.x + acc[r][1] * dv.y + acc[r][2] * dv.z + acc[r][3] * dv.w;
        #pragma unroll
        for (int off = 1; off < G; off <<= 1) {
            pa += __shfl_xor(pa, off);
            pd += __shfl_xor(pd, off);
        }
        if (row < N) {
            *(float4*)&h[(size_t)row * HID + (tx << 2)] =
                make_float4(acc[r][0], acc[r][1], acc[r][2], acc[r][3]);
            if ((tx & (G - 1)) == 0) {
                int hd = tx / G;
                pa_out[(size_t)row * H + hd] = pa;
                pd_out[(size_t)row * H + hd] = pd;
            }
        }
    }
}

// ---------------- aggregation: one wave per dst node, online softmax ----------------
// Gather phase: 2 edges per step — half-wave per edge, float4 (16B) per lane.
template <int H, bool RELU>
__global__ __launch_bounds__(256) void aggregate_kernel(const float* __restrict__ h,
                                                        const float* __restrict__ asrc,
                                                        const float* __restrict__ adst,
                                                        const int* __restrict__ row_ptr,
                                                        const int* __restrict__ col,
                                                        const float* __restrict__ bias,
                                                        float* __restrict__ out, int N) {
    int lane = threadIdx.x & 63;
    int node = blockIdx.x * (blockDim.x >> 6) + (threadIdx.x >> 6);
    if (node >= N) return;

    int start = row_ptr[node];
    int end   = row_ptr[node + 1];

    constexpr int EPC = 64 / H;        // edges per score chunk
    int ehd   = lane % H;              // score phase: head
    int eidx  = lane / H;              // score phase: edge slot
    int epair = lane >> 5;             // gather phase: which edge of the pair
    int cg    = lane & 31;             // gather phase: channels 4cg..4cg+3
    int ahd   = (cg * H) >> 5;         // head owning those channels

    float adst_n = adst[(size_t)node * H + ehd];

    float m = -INFINITY, denom = 0.f;
    float4 acc = make_float4(0.f, 0.f, 0.f, 0.f);

    for (int base = start; base < end; base += EPC) {
        int idx = base + eidx;
        bool valid = idx < end;
        int s = valid ? col[idx] : 0;
        float e = -INFINITY;
        if (valid) {
            float t = asrc[(size_t)s * H + ehd] + adst_n;
            e = (t >= 0.f) ? t : 0.2f * t;
        }
        float cmax = e;
        #pragma unroll
        for (int off = H; off < 64; off <<= 1) cmax = fmaxf(cmax, __shfl_xor(cmax, off));
        float nm = fmaxf(m, cmax);
        float p = valid ? __expf(e - nm) : 0.f;
        float csum = p;
        #pragma unroll
        for (int off = H; off < 64; off <<= 1) csum += __shfl_xor(csum, off);
        float scale_e = __expf(m - nm);     // first chunk: exp(-inf)=0
        denom = denom * scale_e + csum;
        m = nm;
        float sa = __shfl(scale_e, ahd);
        acc.x *= sa; acc.y *= sa; acc.z *= sa; acc.w *= sa;

        int cnt = min(end - base, EPC);
        for (int i = 0; i < cnt; i += 2) {
            int slot = i + epair;                    // <= EPC-1 (EPC even)
            int   si = __shfl(s, slot * H);
            float pi = __shfl(p, slot * H + ahd);
            if (slot < cnt) {
                float4 hv = *(const float4*)&h[(size_t)si * HID + (cg << 2)];
                acc.x += pi * hv.x;
                acc.y += pi * hv.y;
                acc.z += pi * hv.z;
                acc.w += pi * hv.w;
            }
        }
    }
    // combine the two half-wave accumulators
    acc.x += __shfl_xor(acc.x, 32);
    acc.y += __shfl_xor(acc.y, 32);
    acc.z += __shfl_xor(acc.z, 32);
    acc.w += __shfl_xor(acc.w, 32);

    float den = __shfl(denom, ahd);
    if (lane < 32) {
        float inv = 1.f / den;
        float4 bv = *(const float4*)&bias[cg << 2];
        float4 o;
        o.x = acc.x * inv + bv.x;
        o.y = acc.y * inv + bv.y;
        o.z = acc.z * inv + bv.z;
        o.w = acc.w * inv + bv.w;
        if (RELU) {
            o.x = fmaxf(o.x, 0.f); o.y = fmaxf(o.y, 0.f);
            o.z = fmaxf(o.z, 0.f); o.w = fmaxf(o.w, 0.f);
        }
        *(float4*)&out[(size_t)node * HID + (cg << 2)] = o;
    }
}

// ---------------- launch ----------------

extern "C" void kernel_launch(void* const* d_in, const int* in_sizes, int n_in,
                              void* d_out, int out_size, void* d_ws, size_t ws_size,
                              hipStream_t stream) {
    const float* x   = (const float*)d_in[0];
    const int*   ei  = (const int*)d_in[1];
    const float* W1  = (const float*)d_in[2];
    const float* as1 = (const float*)d_in[3];
    const float* ad1 = (const float*)d_in[4];
    const float* b1  = (const float*)d_in[5];
    const float* W2  = (const float*)d_in[6];
    const float* as2 = (const float*)d_in[7];
    const float* ad2 = (const float*)d_in[8];
    const float* b2  = (const float*)d_in[9];
    const float* W3  = (const float*)d_in[10];
    const float* as3 = (const float*)d_in[11];
    const float* ad3 = (const float*)d_in[12];
    const float* b3  = (const float*)d_in[13];

    int N = in_sizes[0] / HID;
    int E = in_sizes[1] / 2;
    const int* srcv = ei;
    const int* dstv = ei + E;

    char* ws = (char*)d_ws;
    size_t ofs = 0;
    auto alloc = [&](size_t bytes) -> void* {
        void* p = ws + ofs;
        ofs = (ofs + bytes + 255) & ~(size_t)255;
        return p;
    };
    int NB = (N + 255) / 256;
    int*   rp   = (int*)alloc((size_t)(N + 1) * 4);
    int*   cur  = (int*)alloc((size_t)N * 4);
    int*   deg  = (int*)alloc((size_t)N * 4);
    int*   bsum = (int*)alloc((size_t)NB * 4);
    int*   boff = (int*)alloc((size_t)NB * 4);
    int*   col  = (int*)alloc((size_t)(E + N) * 4);
    float* h    = (float*)alloc((size_t)N * HID * 4);
    float* pa   = (float*)alloc((size_t)N * 4 * 4);
    float* pd   = (float*)alloc((size_t)N * 4 * 4);
    float* y    = (float*)d_out;   // layers 1-2 output aliases d_out (overwritten by layer 3)

    // CSR build
    deg_init_kernel<<<(N + 255) / 256, 256, 0, stream>>>(deg, N);
    deg_count_kernel<<<(E + 255) / 256, 256, 0, stream>>>(dstv, E, deg);
    scan1_kernel<<<NB, 256, 0, stream>>>(deg, bsum, N);
    scan2_kernel<<<1, 256, 0, stream>>>(bsum, boff, rp, NB, N);
    scan3_kernel<<<NB, 256, 0, stream>>>(deg, boff, rp, cur, col, N);
    scatter_kernel<<<(E + 255) / 256, 256, 0, stream>>>(srcv, dstv, E, cur, col);

    int gGemm = (N + 31) / 32;
    int gWave = (N + 3) / 4;

    // layer 1 (4 heads, relu)
    gemm_alphas_kernel<4><<<gGemm, 256, 0, stream>>>(x, W1, as1, ad1, h, pa, pd, N);
    aggregate_kernel<4, true><<<gWave, 256, 0, stream>>>(h, pa, pd, rp, col, b1, y, N);
    // layer 2 (4 heads, relu)
    gemm_alphas_kernel<4><<<gGemm, 256, 0, stream>>>(y, W2, as2, ad2, h, pa, pd, N);
    aggregate_kernel<4, true><<<gWave, 256, 0, stream>>>(h, pa, pd, rp, col, b2, y, N);
    // layer 3 (1 head, no relu)
    gemm_alphas_kernel<1><<<gGemm, 256, 0, stream>>>(y, W3, as3, ad3, h, pa, pd, N);
    aggregate_kernel<1, false><<<gWave, 256, 0, stream>>>(h, pa, pd, rp, col, b3,
                                                          (float*)d_out, N);
}

// Round 4
// 288.406 us; speedup vs baseline: 1.5557x; 1.0019x over previous
//
#include <hip/hip_runtime.h>
#include <hip/hip_bf16.h>

#define HID 128

// ---------------- CSR build ----------------

__global__ void deg_init_kernel(int* deg, int N) {
    int i = blockIdx.x * blockDim.x + threadIdx.x;
    if (i < N) deg[i] = 1;  // self loop
}

__global__ void deg_count_kernel(const int* __restrict__ dst, int E, int* deg) {
    int i = blockIdx.x * blockDim.x + threadIdx.x;
    if (i < E) atomicAdd(&deg[dst[i]], 1);
}

// --- two-level exclusive scan over N degrees -> row_ptr, cursor, self-loop col ---
__global__ __launch_bounds__(256) void scan1_kernel(const int* __restrict__ deg,
                                                    int* __restrict__ bsum, int N) {
    int tid = threadIdx.x;
    int i = blockIdx.x * 256 + tid;
    int v = (i < N) ? deg[i] : 0;
    #pragma unroll
    for (int off = 1; off < 64; off <<= 1) v += __shfl_xor(v, off);
    __shared__ int ws[4];
    if ((tid & 63) == 0) ws[tid >> 6] = v;
    __syncthreads();
    if (tid == 0) bsum[blockIdx.x] = ws[0] + ws[1] + ws[2] + ws[3];
}

__global__ __launch_bounds__(256) void scan2_kernel(const int* __restrict__ bsum,
                                                    int* __restrict__ boff,
                                                    int* __restrict__ row_ptr, int NB, int N) {
    __shared__ int s[256];
    int tid = threadIdx.x;
    int v = (tid < NB) ? bsum[tid] : 0;
    s[tid] = v;
    __syncthreads();
    for (int off = 1; off < 256; off <<= 1) {
        int t = (tid >= off) ? s[tid - off] : 0;
        __syncthreads();
        s[tid] += t;
        __syncthreads();
    }
    if (tid < NB) boff[tid] = s[tid] - v;  // exclusive
    if (tid == NB - 1) row_ptr[N] = s[tid];
}

__global__ __launch_bounds__(256) void scan3_kernel(const int* __restrict__ deg,
                                                    const int* __restrict__ boff,
                                                    int* __restrict__ row_ptr,
                                                    int* __restrict__ cursor,
                                                    int* __restrict__ col, int N) {
    __shared__ int s[256];
    int tid = threadIdx.x;
    int i = blockIdx.x * 256 + tid;
    int d = (i < N) ? deg[i] : 0;
    s[tid] = d;
    __syncthreads();
    for (int off = 1; off < 256; off <<= 1) {
        int t = (tid >= off) ? s[tid - off] : 0;
        __syncthreads();
        s[tid] += t;
        __syncthreads();
    }
    if (i < N) {
        int run = boff[blockIdx.x] + s[tid] - d;  // exclusive prefix
        row_ptr[i] = run;
        cursor[i] = run + 1;  // slot 0 taken by self loop
        col[run] = i;         // self loop
    }
}

__global__ void scatter_kernel(const int* __restrict__ src, const int* __restrict__ dst,
                               int E, int* cursor, int* col) {
    int i = blockIdx.x * blockDim.x + threadIdx.x;
    if (i < E) {
        int pos = atomicAdd(&cursor[dst[i]], 1);
        col[pos] = src[i];
    }
}

// ---------------- GEMM + fused alpha: h = x @ W, alpha = <h, a> ----------------
// block = 256 threads, 64 rows/block. x tile (32 KB) + W k-chunk (16 KB) in LDS.
// Thread = 8 rows x 4 cols. W staged cooperatively: unique traffic only.
template <int H>
__global__ __launch_bounds__(256) void gemm_alphas_kernel(const float* __restrict__ x,
                                                          const float* __restrict__ W,
                                                          const float* __restrict__ a_src,
                                                          const float* __restrict__ a_dst,
                                                          float* __restrict__ h,
                                                          float* __restrict__ pa_out,
                                                          float* __restrict__ pd_out, int N) {
    __shared__ __align__(16) float xs[64][HID];    // 32 KB
    __shared__ __align__(16) float wsd[32][HID];   // 16 KB (one k-chunk of W)
    int tid = threadIdx.x;
    int row0 = blockIdx.x * 64;
    // stage x tile: 64x128 f32 = 2048 float4, 8 per thread
    #pragma unroll
    for (int t = 0; t < 8; ++t) {
        int f = tid + t * 256;
        int r = f >> 5;
        int c4 = (f & 31) << 2;
        float4 v = make_float4(0.f, 0.f, 0.f, 0.f);
        int row = row0 + r;
        if (row < N) v = *(const float4*)&x[(size_t)row * HID + c4];
        *(float4*)&xs[r][c4] = v;
    }

    int tx = tid & 31;   // col group: cols tx*4..tx*4+3
    int ty = tid >> 5;   // row group: rows ty*8..ty*8+7
    float acc[8][4] = {};

    for (int kc = 0; kc < 4; ++kc) {          // 4 chunks of KC=32
        __syncthreads();
        // stage W chunk: 32x128 = 1024 float4, 4 per thread
        #pragma unroll
        for (int t = 0; t < 4; ++t) {
            int f = tid + t * 256;
            int k = f >> 5;
            int c4 = (f & 31) << 2;
            *(float4*)&wsd[k][c4] = *(const float4*)&W[(size_t)(kc * 32 + k) * HID + c4];
        }
        __syncthreads();
        #pragma unroll
        for (int k4 = 0; k4 < 32; k4 += 4) {
            float wv[4][4];
            #pragma unroll
            for (int kk = 0; kk < 4; ++kk) {
                float4 w = *(const float4*)&wsd[k4 + kk][tx << 2];
                wv[kk][0] = w.x; wv[kk][1] = w.y; wv[kk][2] = w.z; wv[kk][3] = w.w;
            }
            #pragma unroll
            for (int rr = 0; rr < 8; ++rr) {
                float4 xv = *(const float4*)&xs[ty * 8 + rr][kc * 32 + k4];
                float xa[4] = {xv.x, xv.y, xv.z, xv.w};
                #pragma unroll
                for (int kk = 0; kk < 4; ++kk) {
                    acc[rr][0] += xa[kk] * wv[kk][0];
                    acc[rr][1] += xa[kk] * wv[kk][1];
                    acc[rr][2] += xa[kk] * wv[kk][2];
                    acc[rr][3] += xa[kk] * wv[kk][3];
                }
            }
        }
    }

    float4 av = *(const float4*)&a_src[tx << 2];
    float4 dv = *(const float4*)&a_dst[tx << 2];
    constexpr int G = 32 / H;            // lanes per head (within the 32-lane row group)
    #pragma unroll
    for (int rr = 0; rr < 8; ++rr) {
        int row = row0 + ty * 8 + rr;
        float pa = acc[rr][0] * av.x + acc[rr][1] * av.y + acc[rr][2] * av.z + acc[rr][3] * av.w;
        float pd = acc[rr][0] * dv.x + acc[rr][1] * dv.y + acc[rr][2] * dv.z + acc[rr][3] * dv.w;
        #pragma unroll
        for (int off = 1; off < G; off <<= 1) {
            pa += __shfl_xor(pa, off);
            pd += __shfl_xor(pd, off);
        }
        if (row < N) {
            *(float4*)&h[(size_t)row * HID + (tx << 2)] =
                make_float4(acc[rr][0], acc[rr][1], acc[rr][2], acc[rr][3]);
            if ((tx & (G - 1)) == 0) {
                int hd = tx / G;
                pa_out[(size_t)row * H + hd] = pa;
                pd_out[(size_t)row * H + hd] = pd;
            }
        }
    }
}

// ---------------- aggregation: one wave per dst node, online softmax ----------------
// Gather phase: 4 edges in flight — quarter-wave (16 lanes) per edge, 8 ch/lane.
template <int H, bool RELU>
__global__ __launch_bounds__(256) void aggregate_kernel(const float* __restrict__ h,
                                                        const float* __restrict__ asrc,
                                                        const float* __restrict__ adst,
                                                        const int* __restrict__ row_ptr,
                                                        const int* __restrict__ col,
                                                        const float* __restrict__ bias,
                                                        float* __restrict__ out, int N) {
    int lane = threadIdx.x & 63;
    int node = blockIdx.x * (blockDim.x >> 6) + (threadIdx.x >> 6);
    if (node >= N) return;

    int start = row_ptr[node];
    int end   = row_ptr[node + 1];

    constexpr int EPC = 64 / H;        // edges per score chunk
    int ehd = lane % H;                // score phase: head
    int eidx = lane / H;               // score phase: edge slot
    int q  = lane >> 4;                // gather phase: quarter-wave = edge of the quad
    int cl = lane & 15;                // gather phase: channels 8cl..8cl+7
    int ahd = (cl * H) >> 4;           // head owning those channels

    float adst_n = adst[(size_t)node * H + ehd];

    float m = -INFINITY, denom = 0.f;
    float4 acc0 = make_float4(0.f, 0.f, 0.f, 0.f);
    float4 acc1 = make_float4(0.f, 0.f, 0.f, 0.f);

    for (int base = start; base < end; base += EPC) {
        int idx = base + eidx;
        bool valid = idx < end;
        int s = valid ? col[idx] : 0;
        float e = -INFINITY;
        if (valid) {
            float t = asrc[(size_t)s * H + ehd] + adst_n;
            e = (t >= 0.f) ? t : 0.2f * t;
        }
        float cmax = e;
        #pragma unroll
        for (int off = H; off < 64; off <<= 1) cmax = fmaxf(cmax, __shfl_xor(cmax, off));
        float nm = fmaxf(m, cmax);
        float p = valid ? __expf(e - nm) : 0.f;
        float csum = p;
        #pragma unroll
        for (int off = H; off < 64; off <<= 1) csum += __shfl_xor(csum, off);
        float scale_e = __expf(m - nm);     // first chunk: exp(-inf)=0
        denom = denom * scale_e + csum;
        m = nm;
        float sa = __shfl(scale_e, ahd);
        acc0.x *= sa; acc0.y *= sa; acc0.z *= sa; acc0.w *= sa;
        acc1.x *= sa; acc1.y *= sa; acc1.z *= sa; acc1.w *= sa;

        int cnt = min(end - base, EPC);
        #pragma unroll 2
        for (int i = 0; i < cnt; i += 4) {
            int slot = i + q;                         // this quarter-wave's edge
            int   si = __shfl(s, slot * H);           // (shfl idx wraps mod 64; guarded below)
            float pi = __shfl(p, slot * H + ahd);
            if (slot < cnt) {
                const float* hp = &h[(size_t)si * HID + (cl << 3)];
                float4 h0 = *(const float4*)hp;
                float4 h1 = *(const float4*)(hp + 4);
                acc0.x += pi * h0.x; acc0.y += pi * h0.y;
                acc0.z += pi * h0.z; acc0.w += pi * h0.w;
                acc1.x += pi * h1.x; acc1.y += pi * h1.y;
                acc1.z += pi * h1.z; acc1.w += pi * h1.w;
            }
        }
    }
    // combine the four quarter-wave accumulators
    #pragma unroll
    for (int off = 16; off < 64; off <<= 1) {
        acc0.x += __shfl_xor(acc0.x, off); acc0.y += __shfl_xor(acc0.y, off);
        acc0.z += __shfl_xor(acc0.z, off); acc0.w += __shfl_xor(acc0.w, off);
        acc1.x += __shfl_xor(acc1.x, off); acc1.y += __shfl_xor(acc1.y, off);
        acc1.z += __shfl_xor(acc1.z, off); acc1.w += __shfl_xor(acc1.w, off);
    }

    float den = __shfl(denom, ahd);
    if (lane < 16) {
        float inv = 1.f / den;
        float4 b0 = *(const float4*)&bias[cl << 3];
        float4 b1 = *(const float4*)&bias[(cl << 3) + 4];
        float4 o0, o1;
        o0.x = acc0.x * inv + b0.x; o0.y = acc0.y * inv + b0.y;
        o0.z = acc0.z * inv + b0.z; o0.w = acc0.w * inv + b0.w;
        o1.x = acc1.x * inv + b1.x; o1.y = acc1.y * inv + b1.y;
        o1.z = acc1.z * inv + b1.z; o1.w = acc1.w * inv + b1.w;
        if (RELU) {
            o0.x = fmaxf(o0.x, 0.f); o0.y = fmaxf(o0.y, 0.f);
            o0.z = fmaxf(o0.z, 0.f); o0.w = fmaxf(o0.w, 0.f);
            o1.x = fmaxf(o1.x, 0.f); o1.y = fmaxf(o1.y, 0.f);
            o1.z = fmaxf(o1.z, 0.f); o1.w = fmaxf(o1.w, 0.f);
        }
        float* op = &out[(size_t)node * HID + (cl << 3)];
        *(float4*)op = o0;
        *(float4*)(op + 4) = o1;
    }
}

// ---------------- launch ----------------

extern "C" void kernel_launch(void* const* d_in, const int* in_sizes, int n_in,
                              void* d_out, int out_size, void* d_ws, size_t ws_size,
                              hipStream_t stream) {
    const float* x   = (const float*)d_in[0];
    const int*   ei  = (const int*)d_in[1];
    const float* W1  = (const float*)d_in[2];
    const float* as1 = (const float*)d_in[3];
    const float* ad1 = (const float*)d_in[4];
    const float* b1  = (const float*)d_in[5];
    const float* W2  = (const float*)d_in[6];
    const float* as2 = (const float*)d_in[7];
    const float* ad2 = (const float*)d_in[8];
    const float* b2  = (const float*)d_in[9];
    const float* W3  = (const float*)d_in[10];
    const float* as3 = (const float*)d_in[11];
    const float* ad3 = (const float*)d_in[12];
    const float* b3  = (const float*)d_in[13];

    int N = in_sizes[0] / HID;
    int E = in_sizes[1] / 2;
    const int* srcv = ei;
    const int* dstv = ei + E;

    char* ws = (char*)d_ws;
    size_t ofs = 0;
    auto alloc = [&](size_t bytes) -> void* {
        void* p = ws + ofs;
        ofs = (ofs + bytes + 255) & ~(size_t)255;
        return p;
    };
    int NB = (N + 255) / 256;
    int*   rp   = (int*)alloc((size_t)(N + 1) * 4);
    int*   cur  = (int*)alloc((size_t)N * 4);
    int*   deg  = (int*)alloc((size_t)N * 4);
    int*   bsum = (int*)alloc((size_t)NB * 4);
    int*   boff = (int*)alloc((size_t)NB * 4);
    int*   col  = (int*)alloc((size_t)(E + N) * 4);
    float* h    = (float*)alloc((size_t)N * HID * 4);
    float* pa   = (float*)alloc((size_t)N * 4 * 4);
    float* pd   = (float*)alloc((size_t)N * 4 * 4);
    float* y    = (float*)d_out;   // layers 1-2 output aliases d_out (overwritten by layer 3)

    // CSR build
    deg_init_kernel<<<(N + 255) / 256, 256, 0, stream>>>(deg, N);
    deg_count_kernel<<<(E + 255) / 256, 256, 0, stream>>>(dstv, E, deg);
    scan1_kernel<<<NB, 256, 0, stream>>>(deg, bsum, N);
    scan2_kernel<<<1, 256, 0, stream>>>(bsum, boff, rp, NB, N);
    scan3_kernel<<<NB, 256, 0, stream>>>(deg, boff, rp, cur, col, N);
    scatter_kernel<<<(E + 255) / 256, 256, 0, stream>>>(srcv, dstv, E, cur, col);

    int gGemm = (N + 63) / 64;
    int gWave = (N + 3) / 4;

    // layer 1 (4 heads, relu)
    gemm_alphas_kernel<4><<<gGemm, 256, 0, stream>>>(x, W1, as1, ad1, h, pa, pd, N);
    aggregate_kernel<4, true><<<gWave, 256, 0, stream>>>(h, pa, pd, rp, col, b1, y, N);
    // layer 2 (4 heads, relu)
    gemm_alphas_kernel<4><<<gGemm, 256, 0, stream>>>(y, W2, as2, ad2, h, pa, pd, N);
    aggregate_kernel<4, true><<<gWave, 256, 0, stream>>>(h, pa, pd, rp, col, b2, y, N);
    // layer 3 (1 head, no relu)
    gemm_alphas_kernel<1><<<gGemm, 256, 0, stream>>>(y, W3, as3, ad3, h, pa, pd, N);
    aggregate_kernel<1, false><<<gWave, 256, 0, stream>>>(h, pa, pd, rp, col, b3,
                                                          (float*)d_out, N);
}

// Round 5
// 207.610 us; speedup vs baseline: 2.1611x; 1.3892x over previous
//
#include <hip/hip_runtime.h>
#include <hip/hip_bf16.h>

#define HID 128

typedef __attribute__((ext_vector_type(8))) short bf16x8;
typedef __attribute__((ext_vector_type(4))) float f32x4;

__device__ inline unsigned short f2bf(float f) {
    unsigned u = __float_as_uint(f);
    u += 0x7fffu + ((u >> 16) & 1u);   // RNE
    return (unsigned short)(u >> 16);
}
__device__ inline float bfval(unsigned short s) {
    return __uint_as_float(((unsigned)s) << 16);
}

// ---------------- CSR build ----------------

__global__ void deg_init_kernel(int* deg, int N) {
    int i = blockIdx.x * blockDim.x + threadIdx.x;
    if (i < N) deg[i] = 1;  // self loop
}

__global__ void deg_count_kernel(const int* __restrict__ dst, int E, int* deg) {
    int i = blockIdx.x * blockDim.x + threadIdx.x;
    if (i < E) atomicAdd(&deg[dst[i]], 1);
}

__global__ __launch_bounds__(256) void scan1_kernel(const int* __restrict__ deg,
                                                    int* __restrict__ bsum, int N) {
    int tid = threadIdx.x;
    int i = blockIdx.x * 256 + tid;
    int v = (i < N) ? deg[i] : 0;
    #pragma unroll
    for (int off = 1; off < 64; off <<= 1) v += __shfl_xor(v, off);
    __shared__ int ws[4];
    if ((tid & 63) == 0) ws[tid >> 6] = v;
    __syncthreads();
    if (tid == 0) bsum[blockIdx.x] = ws[0] + ws[1] + ws[2] + ws[3];
}

__global__ __launch_bounds__(256) void scan2_kernel(const int* __restrict__ bsum,
                                                    int* __restrict__ boff,
                                                    int* __restrict__ row_ptr, int NB, int N) {
    __shared__ int s[256];
    int tid = threadIdx.x;
    int v = (tid < NB) ? bsum[tid] : 0;
    s[tid] = v;
    __syncthreads();
    for (int off = 1; off < 256; off <<= 1) {
        int t = (tid >= off) ? s[tid - off] : 0;
        __syncthreads();
        s[tid] += t;
        __syncthreads();
    }
    if (tid < NB) boff[tid] = s[tid] - v;  // exclusive
    if (tid == NB - 1) row_ptr[N] = s[tid];
}

__global__ __launch_bounds__(256) void scan3_kernel(const int* __restrict__ deg,
                                                    const int* __restrict__ boff,
                                                    int* __restrict__ row_ptr,
                                                    int* __restrict__ cursor,
                                                    int* __restrict__ col, int N) {
    __shared__ int s[256];
    int tid = threadIdx.x;
    int i = blockIdx.x * 256 + tid;
    int d = (i < N) ? deg[i] : 0;
    s[tid] = d;
    __syncthreads();
    for (int off = 1; off < 256; off <<= 1) {
        int t = (tid >= off) ? s[tid - off] : 0;
        __syncthreads();
        s[tid] += t;
        __syncthreads();
    }
    if (i < N) {
        int run = boff[blockIdx.x] + s[tid] - d;  // exclusive prefix
        row_ptr[i] = run;
        cursor[i] = run + 1;  // slot 0 taken by self loop
        col[run] = i;         // self loop
    }
}

__global__ void scatter_kernel(const int* __restrict__ src, const int* __restrict__ dst,
                               int E, int* cursor, int* col) {
    int i = blockIdx.x * blockDim.x + threadIdx.x;
    if (i < E) {
        int pos = atomicAdd(&cursor[dst[i]], 1);
        col[pos] = src[i];
    }
}

// ---------------- prep: x -> bf16 ----------------
__global__ void tobf16_kernel(const float* __restrict__ x, ushort* __restrict__ xs, int n8) {
    int i = blockIdx.x * blockDim.x + threadIdx.x;   // one per 8 elems
    if (i >= n8) return;
    size_t b = (size_t)i * 8;
    float4 v0 = *(const float4*)&x[b];
    float4 v1 = *(const float4*)&x[b + 4];
    uint4 o;
    o.x = (unsigned)f2bf(v0.x) | ((unsigned)f2bf(v0.y) << 16);
    o.y = (unsigned)f2bf(v0.z) | ((unsigned)f2bf(v0.w) << 16);
    o.z = (unsigned)f2bf(v1.x) | ((unsigned)f2bf(v1.y) << 16);
    o.w = (unsigned)f2bf(v1.z) | ((unsigned)f2bf(v1.w) << 16);
    *(uint4*)&xs[b] = o;
}

// ---------------- prep: W -> MFMA frag layout, hi/lo split ----------------
// wbuf[layer][p][s][t][lane][j]  (ushort), p=0: bf16(W), p=1: bf16(W - hi)
// frag element j for lane l: k = s*32 + (l>>4)*8 + j, c = t*16 + (l&15)
__global__ void prep_w_kernel(const float* __restrict__ W1, const float* __restrict__ W2,
                              const float* __restrict__ W3, ushort* __restrict__ wbuf) {
    int t = blockIdx.x * blockDim.x + threadIdx.x;   // 0 .. 3*4096-1
    if (t >= 3 * 4096) return;
    int layer = t >> 12;
    int rem = t & 4095;
    int lane = rem & 63;
    int tt = (rem >> 6) & 7;
    int s = (rem >> 9) & 3;
    int p = rem >> 11;
    const float* W = (layer == 0) ? W1 : (layer == 1) ? W2 : W3;
    int k0 = s * 32 + (lane >> 4) * 8;
    int c = tt * 16 + (lane & 15);
    ushort out[8];
    #pragma unroll
    for (int j = 0; j < 8; ++j) {
        float w = W[(size_t)(k0 + j) * HID + c];
        unsigned short hi = f2bf(w);
        out[j] = (p == 0) ? hi : f2bf(w - bfval(hi));
    }
    size_t base = (size_t)layer * 32768 + ((((size_t)p * 4 + s) * 8 + tt) * 64 + lane) * 8;
    *(uint4*)&wbuf[base] = *(uint4*)out;
}

// ---------------- MFMA GEMM + fused alphas ----------------
// block = 256 thr = 4 waves, 128 rows. Full W (hi+lo frag layout, 64 KB) in LDS.
// wave: 2 row-groups x 8 col-tiles, K=128, 2 passes (Wh, Wl) -> 128 MFMA.
template <int H>
__global__ __launch_bounds__(256) void mfma_gemm_kernel(const ushort* __restrict__ xs,
                                                        const ushort* __restrict__ wbuf,
                                                        const float* __restrict__ a_src,
                                                        const float* __restrict__ a_dst,
                                                        ushort* __restrict__ h,
                                                        float* __restrict__ pa_out,
                                                        float* __restrict__ pd_out, int N) {
    __shared__ ushort wl[32768];   // 64 KB
    int tid = threadIdx.x;
    // stage W frags: 64 KB, 16B per thread x 16
    #pragma unroll
    for (int t = 0; t < 16; ++t) {
        int i = (t * 256 + tid) * 8;
        *(uint4*)&wl[i] = *(const uint4*)&wbuf[i];
    }
    int wv = tid >> 6, lane = tid & 63;
    int r0 = blockIdx.x * 128 + wv * 32;
    int koff = (lane >> 4) * 8;

    bf16x8 afrag[2][4];
    #pragma unroll
    for (int rg = 0; rg < 2; ++rg) {
        int row = r0 + rg * 16 + (lane & 15);
        if (row >= N) row = N - 1;
        const ushort* xp = &xs[(size_t)row * HID + koff];
        #pragma unroll
        for (int s = 0; s < 4; ++s) afrag[rg][s] = *(const bf16x8*)&xp[s * 32];
    }
    __syncthreads();

    f32x4 acc[2][8];
    #pragma unroll
    for (int rg = 0; rg < 2; ++rg)
        #pragma unroll
        for (int t = 0; t < 8; ++t) acc[rg][t] = (f32x4){0.f, 0.f, 0.f, 0.f};

    #pragma unroll
    for (int p = 0; p < 2; ++p)
        #pragma unroll
        for (int s = 0; s < 4; ++s)
            #pragma unroll
            for (int t = 0; t < 8; ++t) {
                bf16x8 b = *(const bf16x8*)&wl[((((p * 4 + s) * 8) + t) * 64 + lane) * 8];
                acc[0][t] = __builtin_amdgcn_mfma_f32_16x16x32_bf16(afrag[0][s], b, acc[0][t], 0, 0, 0);
                acc[1][t] = __builtin_amdgcn_mfma_f32_16x16x32_bf16(afrag[1][s], b, acc[1][t], 0, 0, 0);
            }

    // epilogue: C/D mapping col = lane&15, row_in_tile = (lane>>4)*4 + j
    int cg = lane >> 4;
    int c = lane & 15;
    #pragma unroll
    for (int rg = 0; rg < 2; ++rg) {
        #pragma unroll
        for (int j = 0; j < 4; ++j) {
            int row = r0 + rg * 16 + cg * 4 + j;
            // per-col products p_t = acc[t][j] * a[t*16+c]; head hd owns t in {2hd,2hd+1}
            if (H == 4) {
                float pah[4], pdh[4];
                #pragma unroll
                for (int hd = 0; hd < 4; ++hd) {
                    float v0 = acc[rg][2 * hd][j], v1 = acc[rg][2 * hd + 1][j];
                    pah[hd] = v0 * a_src[2 * hd * 16 + c] + v1 * a_src[(2 * hd + 1) * 16 + c];
                    pdh[hd] = v0 * a_dst[2 * hd * 16 + c] + v1 * a_dst[(2 * hd + 1) * 16 + c];
                }
                #pragma unroll
                for (int off = 1; off < 16; off <<= 1) {
                    #pragma unroll
                    for (int hd = 0; hd < 4; ++hd) {
                        pah[hd] += __shfl_xor(pah[hd], off);
                        pdh[hd] += __shfl_xor(pdh[hd], off);
                    }
                }
                if (row < N && c == 0) {
                    #pragma unroll
                    for (int hd = 0; hd < 4; ++hd) {
                        pa_out[(size_t)row * 4 + hd] = pah[hd];
                        pd_out[(size_t)row * 4 + hd] = pdh[hd];
                    }
                }
            } else {
                float s1 = 0.f, s2 = 0.f;
                #pragma unroll
                for (int t = 0; t < 8; ++t) {
                    s1 += acc[rg][t][j] * a_src[t * 16 + c];
                    s2 += acc[rg][t][j] * a_dst[t * 16 + c];
                }
                #pragma unroll
                for (int off = 1; off < 16; off <<= 1) {
                    s1 += __shfl_xor(s1, off);
                    s2 += __shfl_xor(s2, off);
                }
                if (row < N && c == 0) { pa_out[row] = s1; pd_out[row] = s2; }
            }
            if (row < N) {
                #pragma unroll
                for (int t = 0; t < 8; ++t)
                    h[(size_t)row * HID + t * 16 + c] = f2bf(acc[rg][t][j]);
            }
        }
    }
}

// ---------------- aggregation: wave per dst node, online softmax, bf16 gather ----------------
template <int H, bool RELU, bool OUTBF>
__global__ __launch_bounds__(256) void aggregate_kernel(const ushort* __restrict__ h,
                                                        const float* __restrict__ asrc,
                                                        const float* __restrict__ adst,
                                                        const int* __restrict__ row_ptr,
                                                        const int* __restrict__ col,
                                                        const float* __restrict__ bias,
                                                        void* __restrict__ outv, int N) {
    int lane = threadIdx.x & 63;
    int node = blockIdx.x * (blockDim.x >> 6) + (threadIdx.x >> 6);
    if (node >= N) return;

    int start = row_ptr[node];
    int end   = row_ptr[node + 1];

    constexpr int EPC = 64 / H;        // edges per score chunk
    int ehd = lane % H;                // score phase: head
    int eidx = lane / H;               // score phase: edge slot
    int q  = lane >> 4;                // gather: quarter-wave = edge of quad
    int cl = lane & 15;                // gather: channels 8cl..8cl+7
    int ahd = (cl * H) >> 4;           // head owning those channels

    float adst_n = adst[(size_t)node * H + ehd];

    float m = -INFINITY, denom = 0.f;
    float acc[8] = {0.f, 0.f, 0.f, 0.f, 0.f, 0.f, 0.f, 0.f};

    for (int base = start; base < end; base += EPC) {
        int idx = base + eidx;
        bool valid = idx < end;
        int s = valid ? col[idx] : 0;
        float e = -INFINITY;
        if (valid) {
            float t = asrc[(size_t)s * H + ehd] + adst_n;
            e = (t >= 0.f) ? t : 0.2f * t;
        }
        float cmax = e;
        #pragma unroll
        for (int off = H; off < 64; off <<= 1) cmax = fmaxf(cmax, __shfl_xor(cmax, off));
        float nm = fmaxf(m, cmax);
        float p = valid ? __expf(e - nm) : 0.f;
        float csum = p;
        #pragma unroll
        for (int off = H; off < 64; off <<= 1) csum += __shfl_xor(csum, off);
        float scale_e = __expf(m - nm);     // first chunk: exp(-inf)=0
        denom = denom * scale_e + csum;
        m = nm;
        float sa = __shfl(scale_e, ahd);
        #pragma unroll
        for (int k = 0; k < 8; ++k) acc[k] *= sa;

        int cnt = min(end - base, EPC);
        for (int i = 0; i < cnt; i += 4) {
            int slot = i + q;
            int   si = __shfl(s, slot * H);
            float pi = __shfl(p, slot * H + ahd);
            if (slot < cnt) {
                uint4 hv = *(const uint4*)&h[(size_t)si * HID + cl * 8];
                acc[0] += pi * __uint_as_float(hv.x << 16);
                acc[1] += pi * __uint_as_float(hv.x & 0xffff0000u);
                acc[2] += pi * __uint_as_float(hv.y << 16);
                acc[3] += pi * __uint_as_float(hv.y & 0xffff0000u);
                acc[4] += pi * __uint_as_float(hv.z << 16);
                acc[5] += pi * __uint_as_float(hv.z & 0xffff0000u);
                acc[6] += pi * __uint_as_float(hv.w << 16);
                acc[7] += pi * __uint_as_float(hv.w & 0xffff0000u);
            }
        }
    }
    // combine the four quarter-wave accumulators
    #pragma unroll
    for (int off = 16; off < 64; off <<= 1) {
        #pragma unroll
        for (int k = 0; k < 8; ++k) acc[k] += __shfl_xor(acc[k], off);
    }

    float den = __shfl(denom, ahd);
    if (lane < 16) {
        float inv = 1.f / den;
        float o[8];
        #pragma unroll
        for (int k = 0; k < 8; ++k) {
            o[k] = acc[k] * inv + bias[cl * 8 + k];
            if (RELU) o[k] = fmaxf(o[k], 0.f);
        }
        if (OUTBF) {
            uint4 ov;
            ov.x = (unsigned)f2bf(o[0]) | ((unsigned)f2bf(o[1]) << 16);
            ov.y = (unsigned)f2bf(o[2]) | ((unsigned)f2bf(o[3]) << 16);
            ov.z = (unsigned)f2bf(o[4]) | ((unsigned)f2bf(o[5]) << 16);
            ov.w = (unsigned)f2bf(o[6]) | ((unsigned)f2bf(o[7]) << 16);
            *(uint4*)&((ushort*)outv)[(size_t)node * HID + cl * 8] = ov;
        } else {
            float* op = &((float*)outv)[(size_t)node * HID + cl * 8];
            *(float4*)op = make_float4(o[0], o[1], o[2], o[3]);
            *(float4*)(op + 4) = make_float4(o[4], o[5], o[6], o[7]);
        }
    }
}

// ---------------- launch ----------------

extern "C" void kernel_launch(void* const* d_in, const int* in_sizes, int n_in,
                              void* d_out, int out_size, void* d_ws, size_t ws_size,
                              hipStream_t stream) {
    const float* x   = (const float*)d_in[0];
    const int*   ei  = (const int*)d_in[1];
    const float* W1  = (const float*)d_in[2];
    const float* as1 = (const float*)d_in[3];
    const float* ad1 = (const float*)d_in[4];
    const float* b1  = (const float*)d_in[5];
    const float* W2  = (const float*)d_in[6];
    const float* as2 = (const float*)d_in[7];
    const float* ad2 = (const float*)d_in[8];
    const float* b2  = (const float*)d_in[9];
    const float* W3  = (const float*)d_in[10];
    const float* as3 = (const float*)d_in[11];
    const float* ad3 = (const float*)d_in[12];
    const float* b3  = (const float*)d_in[13];

    int N = in_sizes[0] / HID;
    int E = in_sizes[1] / 2;
    const int* srcv = ei;
    const int* dstv = ei + E;

    char* ws = (char*)d_ws;
    size_t ofs = 0;
    auto alloc = [&](size_t bytes) -> void* {
        void* p = ws + ofs;
        ofs = (ofs + bytes + 255) & ~(size_t)255;
        return p;
    };
    int NB = (N + 255) / 256;
    int*    rp   = (int*)alloc((size_t)(N + 1) * 4);
    int*    cur  = (int*)alloc((size_t)N * 4);
    int*    deg  = (int*)alloc((size_t)N * 4);
    int*    bsum = (int*)alloc((size_t)NB * 4);
    int*    boff = (int*)alloc((size_t)NB * 4);
    int*    col  = (int*)alloc((size_t)(E + N) * 4);
    ushort* xs   = (ushort*)alloc((size_t)N * HID * 2);   // layer1 input (bf16)
    ushort* ys   = (ushort*)alloc((size_t)N * HID * 2);   // layer2 input
    ushort* hb   = (ushort*)alloc((size_t)N * HID * 2);   // per-layer h (bf16)
    ushort* wbuf = (ushort*)alloc((size_t)3 * 32768 * 2); // W frag layout (hi+lo) x3
    float*  pa   = (float*)alloc((size_t)N * 4 * 4);
    float*  pd   = (float*)alloc((size_t)N * 4 * 4);

    // CSR build
    deg_init_kernel<<<(N + 255) / 256, 256, 0, stream>>>(deg, N);
    deg_count_kernel<<<(E + 255) / 256, 256, 0, stream>>>(dstv, E, deg);
    scan1_kernel<<<NB, 256, 0, stream>>>(deg, bsum, N);
    scan2_kernel<<<1, 256, 0, stream>>>(bsum, boff, rp, NB, N);
    scan3_kernel<<<NB, 256, 0, stream>>>(deg, boff, rp, cur, col, N);
    scatter_kernel<<<(E + 255) / 256, 256, 0, stream>>>(srcv, dstv, E, cur, col);

    // prep
    int n8 = N * HID / 8;
    tobf16_kernel<<<(n8 + 255) / 256, 256, 0, stream>>>(x, xs, n8);
    prep_w_kernel<<<(3 * 4096 + 255) / 256, 256, 0, stream>>>(W1, W2, W3, wbuf);

    int gGemm = (N + 127) / 128;
    int gWave = (N + 3) / 4;

    // layer 1 (4 heads, relu) -> ys
    mfma_gemm_kernel<4><<<gGemm, 256, 0, stream>>>(xs, wbuf, as1, ad1, hb, pa, pd, N);
    aggregate_kernel<4, true, true><<<gWave, 256, 0, stream>>>(hb, pa, pd, rp, col, b1, ys, N);
    // layer 2 (4 heads, relu) -> xs (reuse)
    mfma_gemm_kernel<4><<<gGemm, 256, 0, stream>>>(ys, wbuf + 32768, as2, ad2, hb, pa, pd, N);
    aggregate_kernel<4, true, true><<<gWave, 256, 0, stream>>>(hb, pa, pd, rp, col, b2, xs, N);
    // layer 3 (1 head, no relu) -> d_out fp32
    mfma_gemm_kernel<1><<<gGemm, 256, 0, stream>>>(xs, wbuf + 65536, as3, ad3, hb, pa, pd, N);
    aggregate_kernel<1, false, false><<<gWave, 256, 0, stream>>>(hb, pa, pd, rp, col, b3,
                                                                 d_out, N);
}

// Round 6
// 206.280 us; speedup vs baseline: 2.1750x; 1.0064x over previous
//
#include <hip/hip_runtime.h>
#include <hip/hip_bf16.h>

#define HID 128

typedef __attribute__((ext_vector_type(8))) short bf16x8;
typedef __attribute__((ext_vector_type(4))) float f32x4;

__device__ inline unsigned short f2bf(float f) {
    unsigned u = __float_as_uint(f);
    u += 0x7fffu + ((u >> 16) & 1u);   // RNE
    return (unsigned short)(u >> 16);
}
__device__ inline float bfval(unsigned short s) {
    return __uint_as_float(((unsigned)s) << 16);
}

// ---------------- CSR build ----------------

__global__ void deg_init_kernel(int* deg, int N) {
    int i = blockIdx.x * blockDim.x + threadIdx.x;
    if (i < N) deg[i] = 1;  // self loop
}

__global__ void deg_count_kernel(const int* __restrict__ dst, int E, int* deg) {
    int i = blockIdx.x * blockDim.x + threadIdx.x;
    if (i < E) atomicAdd(&deg[dst[i]], 1);
}

__global__ __launch_bounds__(256) void scan1_kernel(const int* __restrict__ deg,
                                                    int* __restrict__ bsum, int N) {
    int tid = threadIdx.x;
    int i = blockIdx.x * 256 + tid;
    int v = (i < N) ? deg[i] : 0;
    #pragma unroll
    for (int off = 1; off < 64; off <<= 1) v += __shfl_xor(v, off);
    __shared__ int ws[4];
    if ((tid & 63) == 0) ws[tid >> 6] = v;
    __syncthreads();
    if (tid == 0) bsum[blockIdx.x] = ws[0] + ws[1] + ws[2] + ws[3];
}

__global__ __launch_bounds__(256) void scan2_kernel(const int* __restrict__ bsum,
                                                    int* __restrict__ boff,
                                                    int* __restrict__ row_ptr, int NB, int N) {
    __shared__ int s[256];
    int tid = threadIdx.x;
    int v = (tid < NB) ? bsum[tid] : 0;
    s[tid] = v;
    __syncthreads();
    for (int off = 1; off < 256; off <<= 1) {
        int t = (tid >= off) ? s[tid - off] : 0;
        __syncthreads();
        s[tid] += t;
        __syncthreads();
    }
    if (tid < NB) boff[tid] = s[tid] - v;  // exclusive
    if (tid == NB - 1) row_ptr[N] = s[tid];
}

__global__ __launch_bounds__(256) void scan3_kernel(const int* __restrict__ deg,
                                                    const int* __restrict__ boff,
                                                    int* __restrict__ row_ptr,
                                                    int* __restrict__ cursor,
                                                    int* __restrict__ col, int N) {
    __shared__ int s[256];
    int tid = threadIdx.x;
    int i = blockIdx.x * 256 + tid;
    int d = (i < N) ? deg[i] : 0;
    s[tid] = d;
    __syncthreads();
    for (int off = 1; off < 256; off <<= 1) {
        int t = (tid >= off) ? s[tid - off] : 0;
        __syncthreads();
        s[tid] += t;
        __syncthreads();
    }
    if (i < N) {
        int run = boff[blockIdx.x] + s[tid] - d;  // exclusive prefix
        row_ptr[i] = run;
        cursor[i] = run + 1;  // slot 0 taken by self loop
        col[run] = i;         // self loop
    }
}

__global__ void scatter_kernel(const int* __restrict__ src, const int* __restrict__ dst,
                               int E, int* cursor, int* col) {
    int i = blockIdx.x * blockDim.x + threadIdx.x;
    if (i < E) {
        int pos = atomicAdd(&cursor[dst[i]], 1);
        col[pos] = src[i];
    }
}

// ---------------- prep: x -> bf16 ----------------
__global__ void tobf16_kernel(const float* __restrict__ x, ushort* __restrict__ xs, int n8) {
    int i = blockIdx.x * blockDim.x + threadIdx.x;   // one per 8 elems
    if (i >= n8) return;
    size_t b = (size_t)i * 8;
    float4 v0 = *(const float4*)&x[b];
    float4 v1 = *(const float4*)&x[b + 4];
    uint4 o;
    o.x = (unsigned)f2bf(v0.x) | ((unsigned)f2bf(v0.y) << 16);
    o.y = (unsigned)f2bf(v0.z) | ((unsigned)f2bf(v0.w) << 16);
    o.z = (unsigned)f2bf(v1.x) | ((unsigned)f2bf(v1.y) << 16);
    o.w = (unsigned)f2bf(v1.z) | ((unsigned)f2bf(v1.w) << 16);
    *(uint4*)&xs[b] = o;
}

// ---------------- prep: W -> MFMA frag layout, hi/lo split ----------------
// wbuf[layer][p][s][t][lane][j]  (ushort), p=0: bf16(W), p=1: bf16(W - hi)
// frag element j for lane l: k = s*32 + (l>>4)*8 + j, c = t*16 + (l&15)
__global__ void prep_w_kernel(const float* __restrict__ W1, const float* __restrict__ W2,
                              const float* __restrict__ W3, ushort* __restrict__ wbuf) {
    int t = blockIdx.x * blockDim.x + threadIdx.x;   // 0 .. 3*4096-1
    if (t >= 3 * 4096) return;
    int layer = t >> 12;
    int rem = t & 4095;
    int lane = rem & 63;
    int tt = (rem >> 6) & 7;
    int s = (rem >> 9) & 3;
    int p = rem >> 11;
    const float* W = (layer == 0) ? W1 : (layer == 1) ? W2 : W3;
    int k0 = s * 32 + (lane >> 4) * 8;
    int c = tt * 16 + (lane & 15);
    ushort out[8];
    #pragma unroll
    for (int j = 0; j < 8; ++j) {
        float w = W[(size_t)(k0 + j) * HID + c];
        unsigned short hi = f2bf(w);
        out[j] = (p == 0) ? hi : f2bf(w - bfval(hi));
    }
    size_t base = (size_t)layer * 32768 + ((((size_t)p * 4 + s) * 8 + tt) * 64 + lane) * 8;
    *(uint4*)&wbuf[base] = *(uint4*)out;
}

// ---------------- MFMA GEMM + fused alphas (W as A-operand) ----------------
// block = 256 thr = 4 waves, 64 rows (16/wave). Full W (hi+lo frags, 64 KB) in LDS.
// D layout: col(lane&15) = node row, row((lane>>4)*4+j) = out-channel within tile.
// Each lane owns 32 channels of ONE row -> packed 8B h stores, 2-shfl alpha reduce.
template <int H>
__global__ __launch_bounds__(256) void mfma_gemm_kernel(const ushort* __restrict__ xs,
                                                        const ushort* __restrict__ wbuf,
                                                        const float* __restrict__ a_src,
                                                        const float* __restrict__ a_dst,
                                                        ushort* __restrict__ h,
                                                        float* __restrict__ pa_out,
                                                        float* __restrict__ pd_out, int N) {
    __shared__ ushort wl[32768];   // 64 KB
    int tid = threadIdx.x;
    // stage W frags: 64 KB, 16B per thread x 16
    #pragma unroll
    for (int t = 0; t < 16; ++t) {
        int i = (t * 256 + tid) * 8;
        *(uint4*)&wl[i] = *(const uint4*)&wbuf[i];
    }
    int wv = tid >> 6, lane = tid & 63;
    int r0 = blockIdx.x * 64 + wv * 16;
    int koff = (lane >> 4) * 8;

    // B-frag = x rows r0..r0+15 (N-index = lane&15), K = koff + s*32 + j
    int lrow = r0 + (lane & 15);
    if (lrow >= N) lrow = N - 1;
    const ushort* xp = &xs[(size_t)lrow * HID + koff];
    bf16x8 xfrag[4];
    #pragma unroll
    for (int s = 0; s < 4; ++s) xfrag[s] = *(const bf16x8*)&xp[s * 32];
    __syncthreads();

    f32x4 acc[8];
    #pragma unroll
    for (int t = 0; t < 8; ++t) acc[t] = (f32x4){0.f, 0.f, 0.f, 0.f};

    #pragma unroll
    for (int p = 0; p < 2; ++p)
        #pragma unroll
        for (int s = 0; s < 4; ++s)
            #pragma unroll
            for (int t = 0; t < 8; ++t) {
                bf16x8 w = *(const bf16x8*)&wl[((((p * 4 + s) * 8) + t) * 64 + lane) * 8];
                acc[t] = __builtin_amdgcn_mfma_f32_16x16x32_bf16(w, xfrag[s], acc[t], 0, 0, 0);
            }

    // epilogue
    int row = r0 + (lane & 15);
    int cg  = lane >> 4;              // channel group: ch = t*16 + cg*4 + j
    bool rowok = row < N;

    // h store: 8 x 8B packed
    if (rowok) {
        #pragma unroll
        for (int t = 0; t < 8; ++t) {
            uint2 pk;
            pk.x = (unsigned)f2bf(acc[t][0]) | ((unsigned)f2bf(acc[t][1]) << 16);
            pk.y = (unsigned)f2bf(acc[t][2]) | ((unsigned)f2bf(acc[t][3]) << 16);
            *(uint2*)&h[(size_t)row * HID + t * 16 + cg * 4] = pk;
        }
    }

    // alphas: lane partial over its 32 channels, combine across 4 lanes (xor 16,32)
    if (H == 4) {
        float pah[4], pdh[4];
        #pragma unroll
        for (int hd = 0; hd < 4; ++hd) {
            float sa = 0.f, sd = 0.f;
            #pragma unroll
            for (int tt = 0; tt < 2; ++tt) {
                int t = 2 * hd + tt;
                float4 av = *(const float4*)&a_src[t * 16 + cg * 4];
                float4 dv = *(const float4*)&a_dst[t * 16 + cg * 4];
                sa += acc[t][0] * av.x + acc[t][1] * av.y + acc[t][2] * av.z + acc[t][3] * av.w;
                sd += acc[t][0] * dv.x + acc[t][1] * dv.y + acc[t][2] * dv.z + acc[t][3] * dv.w;
            }
            pah[hd] = sa; pdh[hd] = sd;
        }
        #pragma unroll
        for (int off = 16; off < 64; off <<= 1)
            #pragma unroll
            for (int hd = 0; hd < 4; ++hd) {
                pah[hd] += __shfl_xor(pah[hd], off);
                pdh[hd] += __shfl_xor(pdh[hd], off);
            }
        if (rowok && cg == 0) {
            #pragma unroll
            for (int hd = 0; hd < 4; ++hd) {
                pa_out[(size_t)row * 4 + hd] = pah[hd];
                pd_out[(size_t)row * 4 + hd] = pdh[hd];
            }
        }
    } else {
        float sa = 0.f, sd = 0.f;
        #pragma unroll
        for (int t = 0; t < 8; ++t) {
            float4 av = *(const float4*)&a_src[t * 16 + cg * 4];
            float4 dv = *(const float4*)&a_dst[t * 16 + cg * 4];
            sa += acc[t][0] * av.x + acc[t][1] * av.y + acc[t][2] * av.z + acc[t][3] * av.w;
            sd += acc[t][0] * dv.x + acc[t][1] * dv.y + acc[t][2] * dv.z + acc[t][3] * dv.w;
        }
        #pragma unroll
        for (int off = 16; off < 64; off <<= 1) {
            sa += __shfl_xor(sa, off);
            sd += __shfl_xor(sd, off);
        }
        if (rowok && cg == 0) { pa_out[row] = sa; pd_out[row] = sd; }
    }
}

// ---------------- aggregation: wave per dst node, online softmax, bf16 gather ----------------
template <int H, bool RELU, bool OUTBF>
__global__ __launch_bounds__(256) void aggregate_kernel(const ushort* __restrict__ h,
                                                        const float* __restrict__ asrc,
                                                        const float* __restrict__ adst,
                                                        const int* __restrict__ row_ptr,
                                                        const int* __restrict__ col,
                                                        const float* __restrict__ bias,
                                                        void* __restrict__ outv, int N) {
    int lane = threadIdx.x & 63;
    int node = blockIdx.x * (blockDim.x >> 6) + (threadIdx.x >> 6);
    if (node >= N) return;

    int start = row_ptr[node];
    int end   = row_ptr[node + 1];

    constexpr int EPC = 64 / H;        // edges per score chunk
    int ehd = lane % H;                // score phase: head
    int eidx = lane / H;               // score phase: edge slot
    int q  = lane >> 4;                // gather: quarter-wave = edge of quad
    int cl = lane & 15;                // gather: channels 8cl..8cl+7
    int ahd = (cl * H) >> 4;           // head owning those channels

    float adst_n = adst[(size_t)node * H + ehd];

    float m = -INFINITY, denom = 0.f;
    float acc[8] = {0.f, 0.f, 0.f, 0.f, 0.f, 0.f, 0.f, 0.f};

    for (int base = start; base < end; base += EPC) {
        int idx = base + eidx;
        bool valid = idx < end;
        int s = valid ? col[idx] : 0;
        float e = -INFINITY;
        if (valid) {
            float t = asrc[(size_t)s * H + ehd] + adst_n;
            e = (t >= 0.f) ? t : 0.2f * t;
        }
        float cmax = e;
        #pragma unroll
        for (int off = H; off < 64; off <<= 1) cmax = fmaxf(cmax, __shfl_xor(cmax, off));
        float nm = fmaxf(m, cmax);
        float p = valid ? __expf(e - nm) : 0.f;
        float csum = p;
        #pragma unroll
        for (int off = H; off < 64; off <<= 1) csum += __shfl_xor(csum, off);
        float scale_e = __expf(m - nm);     // first chunk: exp(-inf)=0
        denom = denom * scale_e + csum;
        m = nm;
        float sa = __shfl(scale_e, ahd);
        #pragma unroll
        for (int k = 0; k < 8; ++k) acc[k] *= sa;

        int cnt = min(end - base, EPC);
        for (int i = 0; i < cnt; i += 4) {
            int slot = i + q;
            int   si = __shfl(s, slot * H);
            float pi = __shfl(p, slot * H + ahd);
            if (slot < cnt) {
                uint4 hv = *(const uint4*)&h[(size_t)si * HID + cl * 8];
                acc[0] += pi * __uint_as_float(hv.x << 16);
                acc[1] += pi * __uint_as_float(hv.x & 0xffff0000u);
                acc[2] += pi * __uint_as_float(hv.y << 16);
                acc[3] += pi * __uint_as_float(hv.y & 0xffff0000u);
                acc[4] += pi * __uint_as_float(hv.z << 16);
                acc[5] += pi * __uint_as_float(hv.z & 0xffff0000u);
                acc[6] += pi * __uint_as_float(hv.w << 16);
                acc[7] += pi * __uint_as_float(hv.w & 0xffff0000u);
            }
        }
    }
    // combine the four quarter-wave accumulators
    #pragma unroll
    for (int off = 16; off < 64; off <<= 1) {
        #pragma unroll
        for (int k = 0; k < 8; ++k) acc[k] += __shfl_xor(acc[k], off);
    }

    float den = __shfl(denom, ahd);
    if (lane < 16) {
        float inv = 1.f / den;
        float o[8];
        #pragma unroll
        for (int k = 0; k < 8; ++k) {
            o[k] = acc[k] * inv + bias[cl * 8 + k];
            if (RELU) o[k] = fmaxf(o[k], 0.f);
        }
        if (OUTBF) {
            uint4 ov;
            ov.x = (unsigned)f2bf(o[0]) | ((unsigned)f2bf(o[1]) << 16);
            ov.y = (unsigned)f2bf(o[2]) | ((unsigned)f2bf(o[3]) << 16);
            ov.z = (unsigned)f2bf(o[4]) | ((unsigned)f2bf(o[5]) << 16);
            ov.w = (unsigned)f2bf(o[6]) | ((unsigned)f2bf(o[7]) << 16);
            *(uint4*)&((ushort*)outv)[(size_t)node * HID + cl * 8] = ov;
        } else {
            float* op = &((float*)outv)[(size_t)node * HID + cl * 8];
            *(float4*)op = make_float4(o[0], o[1], o[2], o[3]);
            *(float4*)(op + 4) = make_float4(o[4], o[5], o[6], o[7]);
        }
    }
}

// ---------------- launch ----------------

extern "C" void kernel_launch(void* const* d_in, const int* in_sizes, int n_in,
                              void* d_out, int out_size, void* d_ws, size_t ws_size,
                              hipStream_t stream) {
    const float* x   = (const float*)d_in[0];
    const int*   ei  = (const int*)d_in[1];
    const float* W1  = (const float*)d_in[2];
    const float* as1 = (const float*)d_in[3];
    const float* ad1 = (const float*)d_in[4];
    const float* b1  = (const float*)d_in[5];
    const float* W2  = (const float*)d_in[6];
    const float* as2 = (const float*)d_in[7];
    const float* ad2 = (const float*)d_in[8];
    const float* b2  = (const float*)d_in[9];
    const float* W3  = (const float*)d_in[10];
    const float* as3 = (const float*)d_in[11];
    const float* ad3 = (const float*)d_in[12];
    const float* b3  = (const float*)d_in[13];

    int N = in_sizes[0] / HID;
    int E = in_sizes[1] / 2;
    const int* srcv = ei;
    const int* dstv = ei + E;

    char* ws = (char*)d_ws;
    size_t ofs = 0;
    auto alloc = [&](size_t bytes) -> void* {
        void* p = ws + ofs;
        ofs = (ofs + bytes + 255) & ~(size_t)255;
        return p;
    };
    int NB = (N + 255) / 256;
    int*    rp   = (int*)alloc((size_t)(N + 1) * 4);
    int*    cur  = (int*)alloc((size_t)N * 4);
    int*    deg  = (int*)alloc((size_t)N * 4);
    int*    bsum = (int*)alloc((size_t)NB * 4);
    int*    boff = (int*)alloc((size_t)NB * 4);
    int*    col  = (int*)alloc((size_t)(E + N) * 4);
    ushort* xs   = (ushort*)alloc((size_t)N * HID * 2);   // layer1 input (bf16)
    ushort* ys   = (ushort*)alloc((size_t)N * HID * 2);   // layer2 input
    ushort* hb   = (ushort*)alloc((size_t)N * HID * 2);   // per-layer h (bf16)
    ushort* wbuf = (ushort*)alloc((size_t)3 * 32768 * 2); // W frag layout (hi+lo) x3
    float*  pa   = (float*)alloc((size_t)N * 4 * 4);
    float*  pd   = (float*)alloc((size_t)N * 4 * 4);

    // CSR build
    deg_init_kernel<<<(N + 255) / 256, 256, 0, stream>>>(deg, N);
    deg_count_kernel<<<(E + 255) / 256, 256, 0, stream>>>(dstv, E, deg);
    scan1_kernel<<<NB, 256, 0, stream>>>(deg, bsum, N);
    scan2_kernel<<<1, 256, 0, stream>>>(bsum, boff, rp, NB, N);
    scan3_kernel<<<NB, 256, 0, stream>>>(deg, boff, rp, cur, col, N);
    scatter_kernel<<<(E + 255) / 256, 256, 0, stream>>>(srcv, dstv, E, cur, col);

    // prep
    int n8 = N * HID / 8;
    tobf16_kernel<<<(n8 + 255) / 256, 256, 0, stream>>>(x, xs, n8);
    prep_w_kernel<<<(3 * 4096 + 255) / 256, 256, 0, stream>>>(W1, W2, W3, wbuf);

    int gGemm = (N + 63) / 64;
    int gWave = (N + 3) / 4;

    // layer 1 (4 heads, relu) -> ys
    mfma_gemm_kernel<4><<<gGemm, 256, 0, stream>>>(xs, wbuf, as1, ad1, hb, pa, pd, N);
    aggregate_kernel<4, true, true><<<gWave, 256, 0, stream>>>(hb, pa, pd, rp, col, b1, ys, N);
    // layer 2 (4 heads, relu) -> xs (reuse)
    mfma_gemm_kernel<4><<<gGemm, 256, 0, stream>>>(ys, wbuf + 32768, as2, ad2, hb, pa, pd, N);
    aggregate_kernel<4, true, true><<<gWave, 256, 0, stream>>>(hb, pa, pd, rp, col, b2, xs, N);
    // layer 3 (1 head, no relu) -> d_out fp32
    mfma_gemm_kernel<1><<<gGemm, 256, 0, stream>>>(xs, wbuf + 65536, as3, ad3, hb, pa, pd, N);
    aggregate_kernel<1, false, false><<<gWave, 256, 0, stream>>>(hb, pa, pd, rp, col, b3,
                                                                 d_out, N);
}